// Round 11
// baseline (165.685 us; speedup 1.0000x reference)
//
#include <hip/hip_runtime.h>
#include <math.h>

// NeighborList: P = N*(N-1)/2 triu pairs, minimum-image distance, cutoff mask.
// out layout (float32, concatenated): [P] pair_i, [P] pair_j, [P*3] pair_diff, [P] pair_dist
//
// R11: per-PAIR threads at max occupancy. One pair per thread, grid-stride;
// ~35 live VGPRs -> __launch_bounds__(256,8) = 8 waves/SIMD (2x R8's est. 4),
// no LDS slab, no wave_barrier iteration serialization. Stores are naturally
// wave-contiguous: i/j/r are 256B fully-covered lines per instruction; the
// diff stream's 3 stride-12 stores span only 768B per wave (6 lines, fully
// covered by the group -> L2 merge), vs the 3KB span R8 needed LDS to fix.
// R6/R10 proved loads cache-absorbed: plain scalar gathers are fine.
// Carried: int32+f32 solve_ij, reciprocal-mul min-image (rint-safe: flips
// only possible near |delta|~box/2 where the pair is masked either way),
// diag-cell fast path (off-axis terms are d - s*0 == d bit-exactly).

#define NL_CUTOFF 5.0f

// i,j from linear triu pair index p (int32 domain: P < 2^31).
// off(i) = i*(A-i)/2 with A = 2N-1; all products < 2^31.
__device__ __forceinline__ void solve_ij(int p, int N, int& io, int& jo) {
    const int A = 2 * N - 1;
    const int disc = A * A - 8 * p;                 // exact, >= 9
    const float sd = __fsqrt_rn((float)disc);
    int ii = (int)(__fmul_rn(__fsub_rn((float)A, sd), 0.5f));
    if (ii < 0) ii = 0;
    if (ii > N - 2) ii = N - 2;
    while (ii > 0 && ((ii * (A - ii)) >> 1) > p) --ii;
    while ((((ii + 1) * (A - ii - 1)) >> 1) <= p) ++ii;
    io = ii;
    jo = p - ((ii * (A - ii)) >> 1) + ii + 1;
}

struct CellC {
    float r0x, r0y, r0z, rc0;
    float r1x, r1y, r1z, rc1;
    float r2x, r2y, r2z, rc2;
};

template <bool DIAG>
__device__ __forceinline__ void pair_compute(
    float xi, float yi, float zi, float xj, float yj, float zj,
    const CellC& c,
    float& odx, float& ody, float& odz, float& orr, bool& om)
{
    float dx = __fsub_rn(xi, xj);
    float dy = __fsub_rn(yi, yj);
    float dz = __fsub_rn(zi, zj);

    if (DIAG) {
        // diagonal cell: off-axis updates are d - s*0 == d bit-exactly
        float s = rintf(__fmul_rn(dz, c.rc2));
        dz = __fsub_rn(dz, __fmul_rn(s, c.r2z));
        s = rintf(__fmul_rn(dy, c.rc1));
        dy = __fsub_rn(dy, __fmul_rn(s, c.r1y));
        s = rintf(__fmul_rn(dx, c.rc0));
        dx = __fsub_rn(dx, __fmul_rn(s, c.r0x));
    } else {
        float s = rintf(__fmul_rn(dz, c.rc2));
        dx = __fsub_rn(dx, __fmul_rn(s, c.r2x));
        dy = __fsub_rn(dy, __fmul_rn(s, c.r2y));
        dz = __fsub_rn(dz, __fmul_rn(s, c.r2z));

        s = rintf(__fmul_rn(dy, c.rc1));
        dx = __fsub_rn(dx, __fmul_rn(s, c.r1x));
        dy = __fsub_rn(dy, __fmul_rn(s, c.r1y));
        dz = __fsub_rn(dz, __fmul_rn(s, c.r1z));

        s = rintf(__fmul_rn(dx, c.rc0));
        dx = __fsub_rn(dx, __fmul_rn(s, c.r0x));
        dy = __fsub_rn(dy, __fmul_rn(s, c.r0y));
        dz = __fsub_rn(dz, __fmul_rn(s, c.r0z));
    }

    float ss = __fadd_rn(__fadd_rn(__fmul_rn(dx, dx), __fmul_rn(dy, dy)),
                         __fmul_rn(dz, dz));
    float r = __fsqrt_rn(ss);      // correctly rounded: mask boundary bit-exact
    om  = (r < NL_CUTOFF);
    odx = dx;
    ody = dy;
    odz = dz;
    orr = r;
}

template <bool DIAG>
__device__ __forceinline__ void nl_body(
    const float* __restrict__ xyz, const CellC& c,
    float* __restrict__ out, int P, int N)
{
    float* __restrict__ out_i = out;
    float* __restrict__ out_j = out + P;
    float* __restrict__ out_d = out + 2 * (long long)P;   // [P,3] row-major
    float* __restrict__ out_r = out + 5 * (long long)P;

    const int stride = (int)(gridDim.x * blockDim.x);
    const int tid0   = (int)(blockIdx.x * blockDim.x + threadIdx.x);

    for (int p = tid0; p < P; p += stride) {
        int i, j;
        solve_ij(p, N, i, j);

        const float xi = xyz[3 * i + 0], yi = xyz[3 * i + 1], zi = xyz[3 * i + 2];
        const float xj = xyz[3 * j + 0], yj = xyz[3 * j + 1], zj = xyz[3 * j + 2];

        float dx, dy, dz, rr;
        bool  m;
        pair_compute<DIAG>(xi, yi, zi, xj, yj, zj, c, dx, dy, dz, rr, m);

        out_i[p] = m ? (float)i : -1.0f;
        out_j[p] = m ? (float)j : -1.0f;
        out_r[p] = m ? rr : 0.0f;
        out_d[3 * p + 0] = m ? dx : 0.0f;
        out_d[3 * p + 1] = m ? dy : 0.0f;
        out_d[3 * p + 2] = m ? dz : 0.0f;
    }
}

__global__ __launch_bounds__(256, 8) void nl_kernel(
    const float* __restrict__ xyz,
    const float* __restrict__ cell,
    float* __restrict__ out,
    int P, int N)
{
    CellC c;
    c.r0x = cell[0]; c.r0y = cell[1]; c.r0z = cell[2];
    c.r1x = cell[3]; c.r1y = cell[4]; c.r1z = cell[5];
    c.r2x = cell[6]; c.r2y = cell[7]; c.r2z = cell[8];
    c.rc0 = __fdiv_rn(1.0f, c.r0x);
    c.rc1 = __fdiv_rn(1.0f, c.r1y);
    c.rc2 = __fdiv_rn(1.0f, c.r2z);

    const bool diag = (c.r0y == 0.0f) && (c.r0z == 0.0f) &&
                      (c.r1x == 0.0f) && (c.r1z == 0.0f) &&
                      (c.r2x == 0.0f) && (c.r2y == 0.0f);

    if (diag) nl_body<true>(xyz, c, out, P, N);
    else      nl_body<false>(xyz, c, out, P, N);
}

extern "C" void kernel_launch(void* const* d_in, const int* in_sizes, int n_in,
                              void* d_out, int out_size, void* d_ws, size_t ws_size,
                              hipStream_t stream) {
    const float* xyz  = (const float*)d_in[0];
    const float* cell = (const float*)d_in[1];
    float* out = (float*)d_out;

    const int N = in_sizes[0] / 3;
    const int P = in_sizes[2];          // P = N*(N-1)/2 < 2^31 for N=8192

    const int block = 256;
    long long blocks_needed = ((long long)P + block - 1) / block;
    int grid = (int)(blocks_needed < 2048 ? (blocks_needed > 0 ? blocks_needed : 1)
                                          : 2048);

    nl_kernel<<<grid, block, 0, stream>>>(xyz, cell, out, P, N);
}